// Round 2
// baseline (630.577 us; speedup 1.0000x reference)
//
#include <hip/hip_runtime.h>
#include <stdint.h>

constexpr int B = 8, N = 8192, S = 2048, D1 = 128, D2 = 256;
constexpr int CIN = 384, CMID = 256, COUT = 256;

// ---------------------------------------------------------------- top-3 NN
// Packs (idx, weight) into one u32: idx<<21 | round(w*2^21).
__global__ __launch_bounds__(256) void k_top3(const float* __restrict__ xyz1,
                                              const float* __restrict__ xyz2,
                                              uint32_t* __restrict__ pw3) {
  __shared__ float4 xs[S];  // (x, y, z, |x|^2) per source point: 32 KB
  const int b = blockIdx.y;
  const int n = blockIdx.x * 256 + threadIdx.x;
  const float* x2 = xyz2 + (size_t)b * 3 * S;
  for (int s = threadIdx.x; s < S; s += 256) {
    float x = x2[s], y = x2[s + S], z = x2[s + 2 * S];
    xs[s] = make_float4(x, y, z, x * x + y * y + z * z);
  }
  __syncthreads();
  const float* x1 = xyz1 + (size_t)b * 3 * N;
  const float ax = x1[n], ay = x1[n + N], az = x1[n + 2 * N];
  const float n1 = ax * ax + ay * ay + az * az;
  float d0 = 1e30f, d1 = 1e30f, d2 = 1e30f;
  int i0 = 0, i1 = 0, i2 = 0;
#pragma unroll 4
  for (int s = 0; s < S; ++s) {
    float4 p = xs[s];
    // same formula as reference: |x1|^2 + |x2|^2 - 2 x1.x2
    float d = n1 + p.w - 2.0f * (ax * p.x + ay * p.y + az * p.z);
    // strict < keeps lowest-index-first on ties, matching stable top_k
    if (d < d2) {
      if (d < d1) {
        d2 = d1; i2 = i1;
        if (d < d0) { d1 = d0; i1 = i0; d0 = d; i0 = s; }
        else        { d1 = d;  i1 = s; }
      } else { d2 = d; i2 = s; }
    }
  }
  float r0 = 1.0f / (d0 + 1e-8f), r1 = 1.0f / (d1 + 1e-8f), r2 = 1.0f / (d2 + 1e-8f);
  float inv = 1.0f / (r0 + r1 + r2);
  size_t base = ((size_t)b * N + n) * 3;
  auto pack = [](int i, float w) -> uint32_t {
    uint32_t q = (uint32_t)(w * 2097152.0f + 0.5f);
    if (q > 0x1FFFFFu) q = 0x1FFFFFu;
    return ((uint32_t)i << 21) | q;
  };
  pw3[base]     = pack(i0, r0 * inv);
  pw3[base + 1] = pack(i1, r1 * inv);
  pw3[base + 2] = pack(i2, r2 * inv);
}

// ------------------------------------------- conv0: h = W0 @ [interp; p1] + b0
// C-tile 256x64 per block (16 rows x 4 cols per thread), K-tile 16.
__global__ __launch_bounds__(256) void k_gemm0(const float* __restrict__ points1,
                                               const float* __restrict__ points2,
                                               const float* __restrict__ W0,
                                               const float* __restrict__ b0,
                                               const uint32_t* __restrict__ pw3,
                                               float* __restrict__ h) {
  __shared__ float As[16][256];   // W0 slice [k][row]
  __shared__ float Bs[16][64];    // new_points slice [k][col]
  __shared__ int sidx[192];
  __shared__ float sw[192];
  const int tid = threadIdx.x;
  const int b = blockIdx.x >> 7;           // 128 col-blocks per batch
  const int n0 = (blockIdx.x & 127) * 64;
  if (tid < 192) {
    uint32_t p = pw3[((size_t)b * N + n0) * 3 + tid];
    sidx[tid] = (int)(p >> 21);
    sw[tid] = (float)(p & 0x1FFFFFu) * (1.0f / 2097152.0f);
  }
  float acc[4][4][4];
#pragma unroll
  for (int j = 0; j < 4; ++j)
#pragma unroll
    for (int i = 0; i < 4; ++i)
#pragma unroll
      for (int c = 0; c < 4; ++c) acc[j][i][c] = 0.0f;

  const int m = tid & 15;          // row fragment: rows 4m + 64j + i
  const int c0 = (tid >> 4) * 4;   // 4 consecutive cols
  const int sc = tid & 63;         // staging col
  const int skr = (tid >> 6) * 4;  // staging k rows (4 consecutive)

  for (int kk = 0; kk < CIN; kk += 16) {
    __syncthreads();
    {  // stage A: rows = all 256, cols kk..kk+15; thread t handles row t
      const float* wr = W0 + (size_t)tid * CIN + kk;
      float4 w0 = *(const float4*)(wr + 0);
      float4 w1 = *(const float4*)(wr + 4);
      float4 w2 = *(const float4*)(wr + 8);
      float4 wv = *(const float4*)(wr + 12);
      As[0][tid] = w0.x;  As[1][tid] = w0.y;  As[2][tid] = w0.z;  As[3][tid] = w0.w;
      As[4][tid] = w1.x;  As[5][tid] = w1.y;  As[6][tid] = w1.z;  As[7][tid] = w1.w;
      As[8][tid] = w2.x;  As[9][tid] = w2.y;  As[10][tid] = w2.z; As[11][tid] = w2.w;
      As[12][tid] = wv.x; As[13][tid] = wv.y; As[14][tid] = wv.z; As[15][tid] = wv.w;
    }
    if (kk < D2) {  // interp rows: 3-tap weighted gather from points2
      float v0 = 0.f, v1 = 0.f, v2 = 0.f, v3 = 0.f;
#pragma unroll
      for (int j = 0; j < 3; ++j) {
        int id = sidx[sc * 3 + j];
        float w = sw[sc * 3 + j];
        const float* p = points2 + ((size_t)(b * D2 + kk + skr)) * S + id;
        v0 += w * p[0];
        v1 += w * p[S];
        v2 += w * p[2 * S];
        v3 += w * p[3 * S];
      }
      Bs[skr + 0][sc] = v0; Bs[skr + 1][sc] = v1;
      Bs[skr + 2][sc] = v2; Bs[skr + 3][sc] = v3;
    } else {        // points1 rows (coalesced)
      const float* p = points1 + ((size_t)(b * D1 + (kk - D2) + skr)) * N + n0 + sc;
      Bs[skr + 0][sc] = p[0];     Bs[skr + 1][sc] = p[N];
      Bs[skr + 2][sc] = p[2 * N]; Bs[skr + 3][sc] = p[3 * N];
    }
    __syncthreads();
#pragma unroll
    for (int kr = 0; kr < 16; ++kr) {
      float a[16], bv[4];
      *(float4*)&a[0]  = *(const float4*)&As[kr][4 * m];
      *(float4*)&a[4]  = *(const float4*)&As[kr][4 * m + 64];
      *(float4*)&a[8]  = *(const float4*)&As[kr][4 * m + 128];
      *(float4*)&a[12] = *(const float4*)&As[kr][4 * m + 192];
      *(float4*)&bv[0] = *(const float4*)&Bs[kr][c0];
#pragma unroll
      for (int j = 0; j < 4; ++j)
#pragma unroll
        for (int i = 0; i < 4; ++i)
#pragma unroll
          for (int c = 0; c < 4; ++c)
            acc[j][i][c] += a[4 * j + i] * bv[c];
    }
  }
#pragma unroll
  for (int j = 0; j < 4; ++j)
#pragma unroll
    for (int i = 0; i < 4; ++i) {
      int r = 4 * m + 64 * j + i;
      float bias = b0[r];
      float4 o = make_float4(acc[j][i][0] + bias, acc[j][i][1] + bias,
                             acc[j][i][2] + bias, acc[j][i][3] + bias);
      *(float4*)&h[((size_t)(b * CMID + r)) * N + n0 + c0] = o;
    }
}

// ------------------------------------------------- BN batch stats + finalize
__global__ __launch_bounds__(256) void k_stats(const float* __restrict__ h,
                                               const float* __restrict__ gamma,
                                               const float* __restrict__ beta,
                                               float* __restrict__ bna,
                                               float* __restrict__ bnb) {
  const int c = blockIdx.x;
  const int tid = threadIdx.x;
  float sum = 0.f, sq = 0.f;
  for (int b = 0; b < B; ++b) {
    const float* row = h + ((size_t)(b * CMID + c)) * N;
    for (int n = 4 * tid; n < N; n += 1024) {
      float4 v = *(const float4*)(row + n);
      sum += v.x + v.y + v.z + v.w;
      sq += v.x * v.x + v.y * v.y + v.z * v.z + v.w * v.w;
    }
  }
#pragma unroll
  for (int off = 32; off; off >>= 1) {
    sum += __shfl_down(sum, off);
    sq += __shfl_down(sq, off);
  }
  __shared__ float ls[4], lq[4];
  int w = tid >> 6;
  if ((tid & 63) == 0) { ls[w] = sum; lq[w] = sq; }
  __syncthreads();
  if (tid == 0) {
    float s = ls[0] + ls[1] + ls[2] + ls[3];
    float q = lq[0] + lq[1] + lq[2] + lq[3];
    const float invn = 1.0f / (float)(B * N);
    float mean = s * invn;
    float var = q * invn - mean * mean;  // biased, matches reference
    float a = gamma[c] * rsqrtf(var + 1e-5f);
    bna[c] = a;
    bnb[c] = beta[c] - mean * a;
  }
}

// ---------------------- conv1: out = relu(W1 @ relu(a*h+b) + b1), in place
__global__ __launch_bounds__(256) void k_gemm1(const float* __restrict__ W1,
                                               const float* __restrict__ b1,
                                               const float* __restrict__ bna,
                                               const float* __restrict__ bnb,
                                               float* __restrict__ h) {
  __shared__ float As[16][256];
  __shared__ float Bs[16][64];
  __shared__ float sa[256], sb[256];
  const int tid = threadIdx.x;
  const int b = blockIdx.x >> 7;
  const int n0 = (blockIdx.x & 127) * 64;
  sa[tid] = bna[tid];
  sb[tid] = bnb[tid];
  float acc[4][4][4];
#pragma unroll
  for (int j = 0; j < 4; ++j)
#pragma unroll
    for (int i = 0; i < 4; ++i)
#pragma unroll
      for (int c = 0; c < 4; ++c) acc[j][i][c] = 0.0f;

  const int m = tid & 15;
  const int c0 = (tid >> 4) * 4;
  const int sc = tid & 63;
  const int skr = (tid >> 6) * 4;

  for (int kk = 0; kk < CMID; kk += 16) {
    __syncthreads();
    {  // stage A from W1
      const float* wr = W1 + (size_t)tid * CMID + kk;
      float4 w0 = *(const float4*)(wr + 0);
      float4 w1v = *(const float4*)(wr + 4);
      float4 w2 = *(const float4*)(wr + 8);
      float4 wv = *(const float4*)(wr + 12);
      As[0][tid] = w0.x;   As[1][tid] = w0.y;   As[2][tid] = w0.z;   As[3][tid] = w0.w;
      As[4][tid] = w1v.x;  As[5][tid] = w1v.y;  As[6][tid] = w1v.z;  As[7][tid] = w1v.w;
      As[8][tid] = w2.x;   As[9][tid] = w2.y;   As[10][tid] = w2.z;  As[11][tid] = w2.w;
      As[12][tid] = wv.x;  As[13][tid] = wv.y;  As[14][tid] = wv.z;  As[15][tid] = wv.w;
    }
    {  // stage B: BN affine + relu on the fly
      const float* p = h + ((size_t)(b * CMID + kk + skr)) * N + n0 + sc;
#pragma unroll
      for (int jj = 0; jj < 4; ++jj) {
        int k = kk + skr + jj;
        float v = sa[k] * p[(size_t)jj * N] + sb[k];
        Bs[skr + jj][sc] = v > 0.f ? v : 0.f;
      }
    }
    __syncthreads();
#pragma unroll
    for (int kr = 0; kr < 16; ++kr) {
      float a[16], bv[4];
      *(float4*)&a[0]  = *(const float4*)&As[kr][4 * m];
      *(float4*)&a[4]  = *(const float4*)&As[kr][4 * m + 64];
      *(float4*)&a[8]  = *(const float4*)&As[kr][4 * m + 128];
      *(float4*)&a[12] = *(const float4*)&As[kr][4 * m + 192];
      *(float4*)&bv[0] = *(const float4*)&Bs[kr][c0];
#pragma unroll
      for (int j = 0; j < 4; ++j)
#pragma unroll
        for (int i = 0; i < 4; ++i)
#pragma unroll
          for (int c = 0; c < 4; ++c)
            acc[j][i][c] += a[4 * j + i] * bv[c];
    }
  }
  // All global reads of h by this block are done (last read precedes the last
  // __syncthreads); blocks own disjoint columns -> in-place store is safe.
#pragma unroll
  for (int j = 0; j < 4; ++j)
#pragma unroll
    for (int i = 0; i < 4; ++i) {
      int r = 4 * m + 64 * j + i;
      float bias = b1[r];
      float4 o;
      o.x = fmaxf(acc[j][i][0] + bias, 0.f);
      o.y = fmaxf(acc[j][i][1] + bias, 0.f);
      o.z = fmaxf(acc[j][i][2] + bias, 0.f);
      o.w = fmaxf(acc[j][i][3] + bias, 0.f);
      *(float4*)&h[((size_t)(b * CMID + r)) * N + n0 + c0] = o;
    }
}

extern "C" void kernel_launch(void* const* d_in, const int* in_sizes, int n_in,
                              void* d_out, int out_size, void* d_ws, size_t ws_size,
                              hipStream_t stream) {
  const float* xyz1 = (const float*)d_in[0];
  const float* xyz2 = (const float*)d_in[1];
  const float* points1 = (const float*)d_in[2];
  const float* points2 = (const float*)d_in[3];
  const float* W0 = (const float*)d_in[4];
  const float* b0 = (const float*)d_in[5];
  const float* gamma0 = (const float*)d_in[6];
  const float* beta0 = (const float*)d_in[7];
  const float* W1 = (const float*)d_in[8];
  const float* b1 = (const float*)d_in[9];
  float* out = (float*)d_out;  // also used as the h scratch buffer (same shape)

  // Workspace layout (total 788,480 B — kept small; R0's 1.57 MB overran ws):
  //   [0,1KB)      bna       (256 f32)
  //   [1KB,2KB)    bnb       (256 f32)
  //   [2KB,770KB)  pw3       (B*N*3 u32, packed idx|weight)
  char* ws = (char*)d_ws;
  float* bna = (float*)ws;
  float* bnb = (float*)(ws + 1024);
  uint32_t* pw3 = (uint32_t*)(ws + 2048);

  k_top3<<<dim3(N / 256, B), 256, 0, stream>>>(xyz1, xyz2, pw3);
  k_gemm0<<<dim3(B * N / 64), 256, 0, stream>>>(points1, points2, W0, b0, pw3, out);
  k_stats<<<dim3(CMID), 256, 0, stream>>>(out, gamma0, beta0, bna, bnb);
  k_gemm1<<<dim3(B * N / 64), 256, 0, stream>>>(W1, b1, bna, bnb, out);
}

// Round 3
// 483.238 us; speedup vs baseline: 1.3049x; 1.3049x over previous
//
#include <hip/hip_runtime.h>
#include <stdint.h>

constexpr int B = 8, N = 8192, S = 2048, D1 = 128, D2 = 256;
constexpr int CIN = 384, CMID = 256, COUT = 256;

typedef __attribute__((ext_vector_type(8))) _Float16 half8;
typedef __attribute__((ext_vector_type(4))) _Float16 half4;
typedef __attribute__((ext_vector_type(4))) float f32x4;

// ---------------------------------------------------------------- top-3 NN
// Packs (idx, weight) into one u32: idx<<21 | round(w*2^21).
__global__ __launch_bounds__(256) void k_top3(const float* __restrict__ xyz1,
                                              const float* __restrict__ xyz2,
                                              uint32_t* __restrict__ pw3) {
  __shared__ float4 xs[S];  // (x, y, z, |x|^2) per source point: 32 KB
  const int b = blockIdx.y;
  const int n = blockIdx.x * 256 + threadIdx.x;
  const float* x2 = xyz2 + (size_t)b * 3 * S;
  for (int s = threadIdx.x; s < S; s += 256) {
    float x = x2[s], y = x2[s + S], z = x2[s + 2 * S];
    xs[s] = make_float4(x, y, z, x * x + y * y + z * z);
  }
  __syncthreads();
  const float* x1 = xyz1 + (size_t)b * 3 * N;
  const float ax = x1[n], ay = x1[n + N], az = x1[n + 2 * N];
  const float n1 = ax * ax + ay * ay + az * az;
  float d0 = 1e30f, d1 = 1e30f, d2 = 1e30f;
  int i0 = 0, i1 = 0, i2 = 0;
#pragma unroll 4
  for (int s = 0; s < S; ++s) {
    float4 p = xs[s];
    float d = n1 + p.w - 2.0f * (ax * p.x + ay * p.y + az * p.z);
    if (d < d2) {  // strict < keeps lowest-index-first on ties (stable top_k)
      if (d < d1) {
        d2 = d1; i2 = i1;
        if (d < d0) { d1 = d0; i1 = i0; d0 = d; i0 = s; }
        else        { d1 = d;  i1 = s; }
      } else { d2 = d; i2 = s; }
    }
  }
  float r0 = 1.0f / (d0 + 1e-8f), r1 = 1.0f / (d1 + 1e-8f), r2 = 1.0f / (d2 + 1e-8f);
  float inv = 1.0f / (r0 + r1 + r2);
  size_t base = ((size_t)b * N + n) * 3;
  auto pack = [](int i, float w) -> uint32_t {
    uint32_t q = (uint32_t)(w * 2097152.0f + 0.5f);
    if (q > 0x1FFFFFu) q = 0x1FFFFFu;
    return ((uint32_t)i << 21) | q;
  };
  pw3[base]     = pack(i0, r0 * inv);
  pw3[base + 1] = pack(i1, r1 * inv);
  pw3[base + 2] = pack(i2, r2 * inv);
}

// ------------------------------------------- conv0: h = W0 @ [interp; p1] + b0
// fp16 MFMA. Block = 256 threads = 4 waves; C-tile 256 rows x 64 cols.
// Wave w: rows w*64..w*64+63 (4 row-tiles), cols n0..n0+63 (4 col-tiles).
// LDS fragment-chunk layout: X_lds[kb][m] = half8 of X[m][kk+kb*8 .. +8].
__global__ __launch_bounds__(256) void k_gemm0(const float* __restrict__ points1,
                                               const float* __restrict__ points2,
                                               const float* __restrict__ W0,
                                               const float* __restrict__ b0,
                                               const uint32_t* __restrict__ pw3,
                                               float* __restrict__ h) {
  __shared__ half8 A_lds[4][256];  // 16 KB
  __shared__ half8 B_lds[4][64];   // 4 KB
  __shared__ int sidx[192];
  __shared__ float sw[192];
  const int tid = threadIdx.x;
  const int b = blockIdx.x >> 7;          // 128 col-blocks per batch
  const int n0 = (blockIdx.x & 127) * 64;
  if (tid < 192) {
    uint32_t p = pw3[((size_t)b * N + n0) * 3 + tid];
    sidx[tid] = (int)(p >> 21);
    sw[tid] = (float)(p & 0x1FFFFFu) * (1.0f / 2097152.0f);
  }
  f32x4 acc[4][4] = {};
  const int wv = tid >> 6, lane = tid & 63;
  const int ln = lane & 15, quad = lane >> 4;
  const int bn = tid & 63, bkb = tid >> 6;  // B-staging: col, k-chunk
  const int ar = tid >> 3, ac4 = tid & 7;   // A-staging: row base, col4

  for (int kk = 0; kk < CIN; kk += 32) {
    __syncthreads();
    // stage A: W0 rows 0..255, cols kk..kk+31 (coalesced float4 per 8 lanes)
#pragma unroll
    for (int p = 0; p < 8; ++p) {
      int row = ar + 32 * p;
      const float4 v = *(const float4*)(W0 + (size_t)row * CIN + kk + ac4 * 4);
      half4 hv = {(_Float16)v.x, (_Float16)v.y, (_Float16)v.z, (_Float16)v.w};
      *(half4*)((_Float16*)&A_lds[ac4 >> 1][row] + (ac4 & 1) * 4) = hv;
    }
    // stage B: 8 k-rows per thread for column bn
    if (kk < D2) {  // interp: 3-tap weighted gather from points2
      const float* p0 = points2 + ((size_t)(b * D2 + kk + bkb * 8)) * S;
      int j0 = sidx[bn * 3], j1 = sidx[bn * 3 + 1], j2 = sidx[bn * 3 + 2];
      float w0 = sw[bn * 3], w1 = sw[bn * 3 + 1], w2 = sw[bn * 3 + 2];
      half8 ch;
#pragma unroll
      for (int j = 0; j < 8; ++j) {
        const float* pj = p0 + (size_t)j * S;
        ch[j] = (_Float16)(w0 * pj[j0] + w1 * pj[j1] + w2 * pj[j2]);
      }
      B_lds[bkb][bn] = ch;
    } else {        // points1 rows (coalesced)
      const float* p = points1 + ((size_t)(b * D1 + (kk - D2) + bkb * 8)) * N + n0 + bn;
      half8 ch;
#pragma unroll
      for (int j = 0; j < 8; ++j) ch[j] = (_Float16)p[(size_t)j * N];
      B_lds[bkb][bn] = ch;
    }
    __syncthreads();
    half8 af[4], bf[4];
#pragma unroll
    for (int i = 0; i < 4; ++i) af[i] = A_lds[quad][wv * 64 + i * 16 + ln];
#pragma unroll
    for (int j = 0; j < 4; ++j) bf[j] = B_lds[quad][j * 16 + ln];
#pragma unroll
    for (int i = 0; i < 4; ++i)
#pragma unroll
      for (int j = 0; j < 4; ++j)
        acc[i][j] = __builtin_amdgcn_mfma_f32_16x16x32_f16(af[i], bf[j], acc[i][j], 0, 0, 0);
  }
#pragma unroll
  for (int i = 0; i < 4; ++i) {
    int rb = wv * 64 + i * 16 + quad * 4;
#pragma unroll
    for (int reg = 0; reg < 4; ++reg) {
      int row = rb + reg;
      float bias = b0[row];
      float* hr = h + ((size_t)(b * CMID + row)) * N + n0;
#pragma unroll
      for (int j = 0; j < 4; ++j) hr[j * 16 + ln] = acc[i][j][reg] + bias;
    }
  }
}

// ------------------------------------------------- BN batch stats + finalize
__global__ __launch_bounds__(256) void k_stats(const float* __restrict__ h,
                                               const float* __restrict__ gamma,
                                               const float* __restrict__ beta,
                                               float* __restrict__ bna,
                                               float* __restrict__ bnb) {
  const int c = blockIdx.x;
  const int tid = threadIdx.x;
  float sum = 0.f, sq = 0.f;
  for (int b = 0; b < B; ++b) {
    const float* row = h + ((size_t)(b * CMID + c)) * N;
    for (int n = 4 * tid; n < N; n += 1024) {
      float4 v = *(const float4*)(row + n);
      sum += v.x + v.y + v.z + v.w;
      sq += v.x * v.x + v.y * v.y + v.z * v.z + v.w * v.w;
    }
  }
#pragma unroll
  for (int off = 32; off; off >>= 1) {
    sum += __shfl_down(sum, off);
    sq += __shfl_down(sq, off);
  }
  __shared__ float ls[4], lq[4];
  int w = tid >> 6;
  if ((tid & 63) == 0) { ls[w] = sum; lq[w] = sq; }
  __syncthreads();
  if (tid == 0) {
    float s = ls[0] + ls[1] + ls[2] + ls[3];
    float q = lq[0] + lq[1] + lq[2] + lq[3];
    const float invn = 1.0f / (float)(B * N);
    float mean = s * invn;
    float var = q * invn - mean * mean;  // biased, matches reference
    float a = gamma[c] * rsqrtf(var + 1e-5f);
    bna[c] = a;
    bnb[c] = beta[c] - mean * a;
  }
}

// ---------------------- conv1: out = relu(W1 @ relu(a*h+b) + b1), in place
// Same 256x64 fp16-MFMA tile. Blocks own disjoint columns; all global reads
// of h by a block precede its stores -> in-place over h is safe.
__global__ __launch_bounds__(256) void k_gemm1(const float* __restrict__ W1,
                                               const float* __restrict__ b1,
                                               const float* __restrict__ bna,
                                               const float* __restrict__ bnb,
                                               float* __restrict__ h) {
  __shared__ half8 A_lds[4][256];
  __shared__ half8 B_lds[4][64];
  __shared__ float sa[256], sb[256];
  const int tid = threadIdx.x;
  const int b = blockIdx.x >> 7;
  const int n0 = (blockIdx.x & 127) * 64;
  sa[tid] = bna[tid];
  sb[tid] = bnb[tid];
  f32x4 acc[4][4] = {};
  const int wv = tid >> 6, lane = tid & 63;
  const int ln = lane & 15, quad = lane >> 4;
  const int bn = tid & 63, bkb = tid >> 6;
  const int ar = tid >> 3, ac4 = tid & 7;

  for (int kk = 0; kk < CMID; kk += 32) {
    __syncthreads();
#pragma unroll
    for (int p = 0; p < 8; ++p) {
      int row = ar + 32 * p;
      const float4 v = *(const float4*)(W1 + (size_t)row * CMID + kk + ac4 * 4);
      half4 hv = {(_Float16)v.x, (_Float16)v.y, (_Float16)v.z, (_Float16)v.w};
      *(half4*)((_Float16*)&A_lds[ac4 >> 1][row] + (ac4 & 1) * 4) = hv;
    }
    {  // stage B from h with BN affine + relu fused
      const float* p = h + ((size_t)(b * CMID + kk + bkb * 8)) * N + n0 + bn;
      half8 ch;
#pragma unroll
      for (int j = 0; j < 8; ++j) {
        int c = kk + bkb * 8 + j;
        float v = sa[c] * p[(size_t)j * N] + sb[c];
        ch[j] = (_Float16)(v > 0.f ? v : 0.f);
      }
      B_lds[bkb][bn] = ch;
    }
    __syncthreads();
    half8 af[4], bf[4];
#pragma unroll
    for (int i = 0; i < 4; ++i) af[i] = A_lds[quad][wv * 64 + i * 16 + ln];
#pragma unroll
    for (int j = 0; j < 4; ++j) bf[j] = B_lds[quad][j * 16 + ln];
#pragma unroll
    for (int i = 0; i < 4; ++i)
#pragma unroll
      for (int j = 0; j < 4; ++j)
        acc[i][j] = __builtin_amdgcn_mfma_f32_16x16x32_f16(af[i], bf[j], acc[i][j], 0, 0, 0);
  }
#pragma unroll
  for (int i = 0; i < 4; ++i) {
    int rb = wv * 64 + i * 16 + quad * 4;
#pragma unroll
    for (int reg = 0; reg < 4; ++reg) {
      int row = rb + reg;
      float bias = b1[row];
      float* hr = h + ((size_t)(b * CMID + row)) * N + n0;
#pragma unroll
      for (int j = 0; j < 4; ++j)
        hr[j * 16 + ln] = fmaxf(acc[i][j][reg] + bias, 0.f);
    }
  }
}

extern "C" void kernel_launch(void* const* d_in, const int* in_sizes, int n_in,
                              void* d_out, int out_size, void* d_ws, size_t ws_size,
                              hipStream_t stream) {
  const float* xyz1 = (const float*)d_in[0];
  const float* xyz2 = (const float*)d_in[1];
  const float* points1 = (const float*)d_in[2];
  const float* points2 = (const float*)d_in[3];
  const float* W0 = (const float*)d_in[4];
  const float* b0 = (const float*)d_in[5];
  const float* gamma0 = (const float*)d_in[6];
  const float* beta0 = (const float*)d_in[7];
  const float* W1 = (const float*)d_in[8];
  const float* b1 = (const float*)d_in[9];
  float* out = (float*)d_out;  // also the h scratch buffer (same shape)

  // Workspace layout (788,480 B total; ws_size is ~1 MB — do NOT exceed):
  //   [0,1KB) bna | [1KB,2KB) bnb | [2KB,770KB) pw3 (B*N*3 packed idx|weight)
  char* ws = (char*)d_ws;
  float* bna = (float*)ws;
  float* bnb = (float*)(ws + 1024);
  uint32_t* pw3 = (uint32_t*)(ws + 2048);

  k_top3<<<dim3(N / 256, B), 256, 0, stream>>>(xyz1, xyz2, pw3);
  k_gemm0<<<dim3(B * N / 64), 256, 0, stream>>>(points1, points2, W0, b0, pw3, out);
  k_stats<<<dim3(CMID), 256, 0, stream>>>(out, gamma0, beta0, bna, bnb);
  k_gemm1<<<dim3(B * N / 64), 256, 0, stream>>>(W1, b1, bna, bnb, out);
}

// Round 4
// 390.113 us; speedup vs baseline: 1.6164x; 1.2387x over previous
//
#include <hip/hip_runtime.h>
#include <stdint.h>

constexpr int B = 8, N = 8192, S = 2048, D1 = 128, D2 = 256;
constexpr int CIN = 384, CMID = 256, COUT = 256;

typedef __attribute__((ext_vector_type(8))) _Float16 half8;
typedef __attribute__((ext_vector_type(4))) _Float16 half4;
typedef __attribute__((ext_vector_type(4))) float f32x4;

// ---------------------------------------------------------------- top-3 NN
// Block = 4 waves x 64 queries. Wave w scans candidate chunk [512w, 512w+512)
// with wave-uniform scalar loads of xyz2 (SMEM pipe); per-wave top-3 merged
// stably in LDS. Packs (idx, weight) into u32: idx<<21 | round(w*2^21).
__global__ __launch_bounds__(256) void k_top3(const float* __restrict__ xyz1,
                                              const float* __restrict__ xyz2,
                                              uint32_t* __restrict__ pw3) {
  __shared__ float md[4][3][64];
  __shared__ int mi[4][3][64];
  const int tid = threadIdx.x;
  const int wv = tid >> 6, lane = tid & 63;
  const int b = blockIdx.y;
  const int n = blockIdx.x * 64 + lane;  // query (same set for all 4 waves)
  const float* x1 = xyz1 + (size_t)b * 3 * N;
  const float ax = x1[n], ay = x1[n + N], az = x1[n + 2 * N];
  const float* x2 = xyz2 + (size_t)b * 3 * S;

  float d0 = 1e30f, d1 = 1e30f, d2 = 1e30f;
  int i0 = 0, i1 = 0, i2 = 0;
  const int s0 = wv * (S / 4), s1 = s0 + (S / 4);
#pragma unroll 8
  for (int s = s0; s < s1; ++s) {
    float sx = x2[s], sy = x2[s + S], sz = x2[s + 2 * S];  // wave-uniform
    float dx = ax - sx, dy = ay - sy, dz = az - sz;
    float d = dx * dx + dy * dy + dz * dz;
    if (d < d2) {  // strict < : stable (lowest index wins ties)
      if (d < d1) {
        d2 = d1; i2 = i1;
        if (d < d0) { d1 = d0; i1 = i0; d0 = d; i0 = s; }
        else        { d1 = d;  i1 = s; }
      } else { d2 = d; i2 = s; }
    }
  }
  md[wv][0][lane] = d0; mi[wv][0][lane] = i0;
  md[wv][1][lane] = d1; mi[wv][1][lane] = i1;
  md[wv][2][lane] = d2; mi[wv][2][lane] = i2;
  __syncthreads();
  if (tid < 64) {
    float e0 = md[0][0][tid], e1 = md[0][1][tid], e2 = md[0][2][tid];
    int j0 = mi[0][0][tid], j1 = mi[0][1][tid], j2 = mi[0][2][tid];
#pragma unroll
    for (int w = 1; w < 4; ++w)
#pragma unroll
      for (int k = 0; k < 3; ++k) {
        float d = md[w][k][tid];
        int i = mi[w][k][tid];
        // ascending-s wave order + strict < keeps reference tie-breaking
        if (d < e2) {
          if (d < e1) {
            e2 = e1; j2 = j1;
            if (d < e0) { e1 = e0; j1 = j0; e0 = d; j0 = i; }
            else        { e1 = d;  j1 = i; }
          } else { e2 = d; j2 = i; }
        }
      }
    float r0 = 1.0f / (e0 + 1e-8f), r1 = 1.0f / (e1 + 1e-8f), r2 = 1.0f / (e2 + 1e-8f);
    float inv = 1.0f / (r0 + r1 + r2);
    auto pack = [](int i, float w) -> uint32_t {
      uint32_t q = (uint32_t)(w * 2097152.0f + 0.5f);
      if (q > 0x1FFFFFu) q = 0x1FFFFFu;
      return ((uint32_t)i << 21) | q;
    };
    size_t base = ((size_t)b * N + blockIdx.x * 64 + tid) * 3;
    pw3[base]     = pack(j0, r0 * inv);
    pw3[base + 1] = pack(j1, r1 * inv);
    pw3[base + 2] = pack(j2, r2 * inv);
  }
}

// ------------------------------------------- conv0: h = W0 @ [interp; p1] + b0
// fp16 MFMA. Block = 256 threads = 4 waves; C-tile 256 rows x 64 cols.
// LDS fragment-chunk layout: X_lds[kb][m] = half8 of X[m][kk+kb*8 .. +8].
__global__ __launch_bounds__(256) void k_gemm0(const float* __restrict__ points1,
                                               const float* __restrict__ points2,
                                               const float* __restrict__ W0,
                                               const float* __restrict__ b0,
                                               const uint32_t* __restrict__ pw3,
                                               float* __restrict__ h) {
  __shared__ half8 A_lds[4][256];  // 16 KB
  __shared__ half8 B_lds[4][64];   // 4 KB
  __shared__ int sidx[192];
  __shared__ float sw[192];
  const int tid = threadIdx.x;
  const int b = blockIdx.x >> 7;          // 128 col-blocks per batch
  const int n0 = (blockIdx.x & 127) * 64;
  if (tid < 192) {
    uint32_t p = pw3[((size_t)b * N + n0) * 3 + tid];
    sidx[tid] = (int)(p >> 21);
    sw[tid] = (float)(p & 0x1FFFFFu) * (1.0f / 2097152.0f);
  }
  f32x4 acc[4][4] = {};
  const int wv = tid >> 6, lane = tid & 63;
  const int ln = lane & 15, quad = lane >> 4;
  const int bn = tid & 63, bkb = tid >> 6;  // B-staging: col, k-chunk
  const int ar = tid >> 3, ac4 = tid & 7;   // A-staging: row base, col4

  for (int kk = 0; kk < CIN; kk += 32) {
    __syncthreads();
    // stage A: W0 rows 0..255, cols kk..kk+31 (coalesced float4 per 8 lanes)
#pragma unroll
    for (int p = 0; p < 8; ++p) {
      int row = ar + 32 * p;
      const float4 v = *(const float4*)(W0 + (size_t)row * CIN + kk + ac4 * 4);
      half4 hv = {(_Float16)v.x, (_Float16)v.y, (_Float16)v.z, (_Float16)v.w};
      *(half4*)((_Float16*)&A_lds[ac4 >> 1][row] + (ac4 & 1) * 4) = hv;
    }
    // stage B: 8 k-rows per thread for column bn
    if (kk < D2) {  // interp: 3-tap weighted gather from points2
      const float* p0 = points2 + ((size_t)(b * D2 + kk + bkb * 8)) * S;
      int j0 = sidx[bn * 3], j1 = sidx[bn * 3 + 1], j2 = sidx[bn * 3 + 2];
      float w0 = sw[bn * 3], w1 = sw[bn * 3 + 1], w2 = sw[bn * 3 + 2];
      half8 ch;
#pragma unroll
      for (int j = 0; j < 8; ++j) {
        const float* pj = p0 + (size_t)j * S;
        ch[j] = (_Float16)(w0 * pj[j0] + w1 * pj[j1] + w2 * pj[j2]);
      }
      B_lds[bkb][bn] = ch;
    } else {        // points1 rows (coalesced)
      const float* p = points1 + ((size_t)(b * D1 + (kk - D2) + bkb * 8)) * N + n0 + bn;
      half8 ch;
#pragma unroll
      for (int j = 0; j < 8; ++j) ch[j] = (_Float16)p[(size_t)j * N];
      B_lds[bkb][bn] = ch;
    }
    __syncthreads();
    half8 af[4], bf[4];
#pragma unroll
    for (int i = 0; i < 4; ++i) af[i] = A_lds[quad][wv * 64 + i * 16 + ln];
#pragma unroll
    for (int j = 0; j < 4; ++j) bf[j] = B_lds[quad][j * 16 + ln];
#pragma unroll
    for (int i = 0; i < 4; ++i)
#pragma unroll
      for (int j = 0; j < 4; ++j)
        acc[i][j] = __builtin_amdgcn_mfma_f32_16x16x32_f16(af[i], bf[j], acc[i][j], 0, 0, 0);
  }
#pragma unroll
  for (int i = 0; i < 4; ++i) {
    int rb = wv * 64 + i * 16 + quad * 4;
#pragma unroll
    for (int reg = 0; reg < 4; ++reg) {
      int row = rb + reg;
      float bias = b0[row];
      float* hr = h + ((size_t)(b * CMID + row)) * N + n0;
#pragma unroll
      for (int j = 0; j < 4; ++j) hr[j * 16 + ln] = acc[i][j][reg] + bias;
    }
  }
}

// ------------------------------------------------- BN batch stats + finalize
__global__ __launch_bounds__(256) void k_stats(const float* __restrict__ h,
                                               const float* __restrict__ gamma,
                                               const float* __restrict__ beta,
                                               float* __restrict__ bna,
                                               float* __restrict__ bnb) {
  const int c = blockIdx.x;
  const int tid = threadIdx.x;
  float sum = 0.f, sq = 0.f;
  for (int b = 0; b < B; ++b) {
    const float* row = h + ((size_t)(b * CMID + c)) * N;
    for (int n = 4 * tid; n < N; n += 1024) {
      float4 v = *(const float4*)(row + n);
      sum += v.x + v.y + v.z + v.w;
      sq += v.x * v.x + v.y * v.y + v.z * v.z + v.w * v.w;
    }
  }
#pragma unroll
  for (int off = 32; off; off >>= 1) {
    sum += __shfl_down(sum, off);
    sq += __shfl_down(sq, off);
  }
  __shared__ float ls[4], lq[4];
  int w = tid >> 6;
  if ((tid & 63) == 0) { ls[w] = sum; lq[w] = sq; }
  __syncthreads();
  if (tid == 0) {
    float s = ls[0] + ls[1] + ls[2] + ls[3];
    float q = lq[0] + lq[1] + lq[2] + lq[3];
    const float invn = 1.0f / (float)(B * N);
    float mean = s * invn;
    float var = q * invn - mean * mean;  // biased, matches reference
    float a = gamma[c] * rsqrtf(var + 1e-5f);
    bna[c] = a;
    bnb[c] = beta[c] - mean * a;
  }
}

// ---------------------- conv1: out = relu(W1 @ relu(a*h+b) + b1), in place
// Blocks own disjoint columns; all global reads of h by a block precede its
// stores -> in-place over h is safe.
__global__ __launch_bounds__(256) void k_gemm1(const float* __restrict__ W1,
                                               const float* __restrict__ b1,
                                               const float* __restrict__ bna,
                                               const float* __restrict__ bnb,
                                               float* __restrict__ h) {
  __shared__ half8 A_lds[4][256];
  __shared__ half8 B_lds[4][64];
  __shared__ float sa[256], sb[256];
  const int tid = threadIdx.x;
  const int b = blockIdx.x >> 7;
  const int n0 = (blockIdx.x & 127) * 64;
  sa[tid] = bna[tid];
  sb[tid] = bnb[tid];
  f32x4 acc[4][4] = {};
  const int wv = tid >> 6, lane = tid & 63;
  const int ln = lane & 15, quad = lane >> 4;
  const int bn = tid & 63, bkb = tid >> 6;
  const int ar = tid >> 3, ac4 = tid & 7;

  for (int kk = 0; kk < CMID; kk += 32) {
    __syncthreads();
#pragma unroll
    for (int p = 0; p < 8; ++p) {
      int row = ar + 32 * p;
      const float4 v = *(const float4*)(W1 + (size_t)row * CMID + kk + ac4 * 4);
      half4 hv = {(_Float16)v.x, (_Float16)v.y, (_Float16)v.z, (_Float16)v.w};
      *(half4*)((_Float16*)&A_lds[ac4 >> 1][row] + (ac4 & 1) * 4) = hv;
    }
    {  // stage B from h with BN affine + relu fused
      const float* p = h + ((size_t)(b * CMID + kk + bkb * 8)) * N + n0 + bn;
      half8 ch;
#pragma unroll
      for (int j = 0; j < 8; ++j) {
        int c = kk + bkb * 8 + j;
        float v = sa[c] * p[(size_t)j * N] + sb[c];
        ch[j] = (_Float16)(v > 0.f ? v : 0.f);
      }
      B_lds[bkb][bn] = ch;
    }
    __syncthreads();
    half8 af[4], bf[4];
#pragma unroll
    for (int i = 0; i < 4; ++i) af[i] = A_lds[quad][wv * 64 + i * 16 + ln];
#pragma unroll
    for (int j = 0; j < 4; ++j) bf[j] = B_lds[quad][j * 16 + ln];
#pragma unroll
    for (int i = 0; i < 4; ++i)
#pragma unroll
      for (int j = 0; j < 4; ++j)
        acc[i][j] = __builtin_amdgcn_mfma_f32_16x16x32_f16(af[i], bf[j], acc[i][j], 0, 0, 0);
  }
#pragma unroll
  for (int i = 0; i < 4; ++i) {
    int rb = wv * 64 + i * 16 + quad * 4;
#pragma unroll
    for (int reg = 0; reg < 4; ++reg) {
      int row = rb + reg;
      float bias = b1[row];
      float* hr = h + ((size_t)(b * CMID + row)) * N + n0;
#pragma unroll
      for (int j = 0; j < 4; ++j)
        hr[j * 16 + ln] = fmaxf(acc[i][j][reg] + bias, 0.f);
    }
  }
}

extern "C" void kernel_launch(void* const* d_in, const int* in_sizes, int n_in,
                              void* d_out, int out_size, void* d_ws, size_t ws_size,
                              hipStream_t stream) {
  const float* xyz1 = (const float*)d_in[0];
  const float* xyz2 = (const float*)d_in[1];
  const float* points1 = (const float*)d_in[2];
  const float* points2 = (const float*)d_in[3];
  const float* W0 = (const float*)d_in[4];
  const float* b0 = (const float*)d_in[5];
  const float* gamma0 = (const float*)d_in[6];
  const float* beta0 = (const float*)d_in[7];
  const float* W1 = (const float*)d_in[8];
  const float* b1 = (const float*)d_in[9];
  float* out = (float*)d_out;  // also the h scratch buffer (same shape)

  // Workspace layout (788,480 B total; keep below ~1 MB — R0 overran at 1.57MB)
  //   [0,1KB) bna | [1KB,2KB) bnb | [2KB,770KB) pw3 (B*N*3 packed idx|weight)
  char* ws = (char*)d_ws;
  float* bna = (float*)ws;
  float* bnb = (float*)(ws + 1024);
  uint32_t* pw3 = (uint32_t*)(ws + 2048);

  k_top3<<<dim3(N / 64, B), 256, 0, stream>>>(xyz1, xyz2, pw3);
  k_gemm0<<<dim3(B * N / 64), 256, 0, stream>>>(points1, points2, W0, b0, pw3, out);
  k_stats<<<dim3(CMID), 256, 0, stream>>>(out, gamma0, beta0, bna, bnb);
  k_gemm1<<<dim3(B * N / 64), 256, 0, stream>>>(W1, b1, bna, bnb, out);
}